// Round 1
// baseline (9192.150 us; speedup 1.0000x reference)
//
#include <hip/hip_runtime.h>
#include <math.h>

static const int NN  = 16384;   // nodes
static const int NE  = 524288;  // edges
static const int KNN_K = 16;
static const int KEDGE = 17;    // k + self loop
static const int SCC = 512;     // sim column chunk
static const int NCH = 1024;    // node chunk for dynamic edge MLP

// ---------------- utility fills ----------------
__global__ void k_fill_f32(float* p, float v, int n){
  int i = blockIdx.x*256 + threadIdx.x; if (i < n) p[i] = v;
}
__global__ void k_fill_i32(int* p, int v, int n){
  int i = blockIdx.x*256 + threadIdx.x; if (i < n) p[i] = v;
}

// ---------------- CSR build (dst-sorted) ----------------
__global__ void k_hist(const int* __restrict__ dst, int* __restrict__ cnt){
  int e = blockIdx.x*256 + threadIdx.x; if (e < NE) atomicAdd(&cnt[dst[e]], 1);
}
__global__ void k_scan(const int* __restrict__ cnt, int* __restrict__ off){
  __shared__ int part[1024];
  int t = threadIdx.x;
  int base = t*16;
  int loc[16]; int s = 0;
#pragma unroll
  for (int q=0;q<16;q++){ loc[q] = s; s += cnt[base+q]; }
  part[t] = s; __syncthreads();
  for (int d=1; d<1024; d<<=1){
    int v = (t>=d) ? part[t-d] : 0; __syncthreads();
    part[t] += v; __syncthreads();
  }
  int prev = (t==0) ? 0 : part[t-1];
#pragma unroll
  for (int q=0;q<16;q++) off[base+q] = prev + loc[q];
  if (t == 1023) off[NN] = part[1023];
}
__global__ void k_csr_fill(const int* __restrict__ src, const int* __restrict__ dst,
                           const int* __restrict__ off, int* __restrict__ cur,
                           int* __restrict__ csrc, int* __restrict__ ceid){
  int e = blockIdx.x*256 + threadIdx.x; if (e >= NE) return;
  int d = dst[e];
  int p = atomicAdd(&cur[d], 1);
  int idx = off[d] + p;
  csrc[idx] = src[e];
  ceid[idx] = e;
}

// ---------------- static layer segment-max (gather form) ----------------
// h[i][c<Dx]  = max_e x[src_e][c] - x[i][c]   (0 if no edges)
// h[i][c>=Dx] = max_e ea[e][c-Dx]             (0 if no edges)
__global__ void k_static_segmax(const float* __restrict__ x, int Dx,
                                const float* __restrict__ ea,
                                const int* __restrict__ off,
                                const int* __restrict__ csrc,
                                const int* __restrict__ ceid,
                                float* __restrict__ h){
  int i = blockIdx.x, c = threadIdx.x;
  int DM = Dx + 64;
  int s = off[i], e = off[i+1];
  float m = -INFINITY;
  if (c < Dx){
    for (int t = s; t < e; t++) m = fmaxf(m, x[(size_t)csrc[t]*Dx + c]);
    h[(size_t)i*DM + c] = (s == e) ? 0.f : (m - x[(size_t)i*Dx + c]);
  } else {
    int cc = c - Dx;
    for (int t = s; t < e; t++) m = fmaxf(m, ea[(size_t)ceid[t]*64 + cc]);
    h[(size_t)i*DM + c] = (s == e) ? 0.f : m;
  }
}

// ---------------- generic fp32 GEMM ----------------
// C[M,Nc] (ldc) = f(A[M,K](lda) @ B) with optional += ; slope=1 -> identity.
// BTRANS=0: B is [K,Nc] row-major (ldb). BTRANS=1: B is [*,K] row-major, C=A@B^T.
// diagneg: write -inf where global row m == colbase + n (kNN self mask).
// M must be a multiple of 64, K a multiple of 16.
template<int BTRANS>
__global__ __launch_bounds__(256) void k_gemm(
    const float* __restrict__ A, int lda,
    const float* __restrict__ B, int ldb,
    float* __restrict__ C, int ldc,
    int K, int Nc, float slope, int accum, int diagneg, int colbase)
{
  __shared__ float As[16][64];
  __shared__ float Bs[16][64];
  int t = threadIdx.x;
  int m0 = blockIdx.y*64, n0 = blockIdx.x*64;
  int ty = t >> 4, tx = t & 15;
  float acc[4][4] = {};
  int ar = t >> 2, akq = (t & 3) << 2;
  for (int k0 = 0; k0 < K; k0 += 16){
    float4 av = *(const float4*)(A + (size_t)(m0+ar)*lda + k0 + akq);
    As[akq+0][ar]=av.x; As[akq+1][ar]=av.y; As[akq+2][ar]=av.z; As[akq+3][ar]=av.w;
    if (BTRANS){
      float4 bv = *(const float4*)(B + (size_t)(n0+ar)*ldb + k0 + akq);
      Bs[akq+0][ar]=bv.x; Bs[akq+1][ar]=bv.y; Bs[akq+2][ar]=bv.z; Bs[akq+3][ar]=bv.w;
    } else {
      int bk = t >> 4, bn = (t & 15) << 2;
      float4 bv = make_float4(0.f,0.f,0.f,0.f);
      if (n0 + bn < Nc) bv = *(const float4*)(B + (size_t)(k0+bk)*ldb + n0 + bn);
      Bs[bk][bn+0]=bv.x; Bs[bk][bn+1]=bv.y; Bs[bk][bn+2]=bv.z; Bs[bk][bn+3]=bv.w;
    }
    __syncthreads();
#pragma unroll
    for (int k=0;k<16;k++){
      float4 a = *(const float4*)&As[k][ty<<2];
      float4 b = *(const float4*)&Bs[k][tx<<2];
      acc[0][0]+=a.x*b.x; acc[0][1]+=a.x*b.y; acc[0][2]+=a.x*b.z; acc[0][3]+=a.x*b.w;
      acc[1][0]+=a.y*b.x; acc[1][1]+=a.y*b.y; acc[1][2]+=a.y*b.z; acc[1][3]+=a.y*b.w;
      acc[2][0]+=a.z*b.x; acc[2][1]+=a.z*b.y; acc[2][2]+=a.z*b.z; acc[2][3]+=a.z*b.w;
      acc[3][0]+=a.w*b.x; acc[3][1]+=a.w*b.y; acc[3][2]+=a.w*b.z; acc[3][3]+=a.w*b.w;
    }
    __syncthreads();
  }
#pragma unroll
  for (int i2=0;i2<4;i2++){
    int m = m0 + (ty<<2) + i2;
#pragma unroll
    for (int j=0;j<4;j++){
      int n = n0 + (tx<<2) + j;
      if (n < Nc){
        float v = acc[i2][j];
        if (diagneg && m == colbase + n) v = -INFINITY;
        else v = (v >= 0.f) ? v : v*slope;
        size_t idx = (size_t)m*ldc + n;
        C[idx] = accum ? (C[idx] + v) : v;
      }
    }
  }
}

// ---------------- kNN pieces ----------------
__global__ void k_normalize(const float* __restrict__ x, float* __restrict__ xn, int Dx){
  int i = blockIdx.x, lane = threadIdx.x;   // 64 lanes
  float a = x[(size_t)i*Dx + lane];
  float b = (Dx == 128) ? x[(size_t)i*Dx + 64 + lane] : 0.f;
  float ss = a*a + b*b;
  for (int d = 32; d; d >>= 1) ss += __shfl_xor(ss, d);
  float rs = rsqrtf(ss + 1e-12f);
  xn[(size_t)i*Dx + lane] = a*rs;
  if (Dx == 128) xn[(size_t)i*Dx + 64 + lane] = b*rs;
}

// one wave per row; merge SCC chunk candidates into running top-16
// tie-break: larger value, then smaller index (matches jax.lax.top_k set)
__global__ void k_topk_merge(const float* __restrict__ S, int colbase,
                             float* __restrict__ topv, int* __restrict__ topi){
  int i = blockIdx.x;
  int lane = threadIdx.x;  // 64
  const float* row = S + (size_t)i * SCC;
  float cv[8]; int cj[8];
#pragma unroll
  for (int q=0;q<8;q++){
    int lc = lane + (q<<6);
    float v = row[lc];
    int j = colbase + lc;
    if (j == i) v = -INFINITY;
    cv[q]=v; cj[q]=j;
  }
  float pv = -INFINITY; int pj = 0x7fffffff;
  if (lane < 16){ pv = topv[i*16+lane]; pj = topi[i*16+lane]; }
  float myv = -INFINITY; int myj = 0;
#pragma unroll
  for (int r=0;r<16;r++){
    float lv = pv; int lj = pj;
#pragma unroll
    for (int q=0;q<8;q++){
      bool better = (cv[q] > lv) || (cv[q] == lv && cj[q] < lj);
      if (better){ lv = cv[q]; lj = cj[q]; }
    }
    float bv = lv; int bj = lj;
    for (int d=32; d; d>>=1){
      float ov = __shfl_xor(bv, d);
      int oj = __shfl_xor(bj, d);
      bool better = (ov > bv) || (ov == bv && oj < bj);
      if (better){ bv = ov; bj = oj; }
    }
    if (lj == bj){              // owner lane removes the winner
      if (pj == bj) pv = -INFINITY;
      else {
#pragma unroll
        for (int q=0;q<8;q++) if (cj[q] == bj) cv[q] = -INFINITY;
      }
    }
    if (lane == r){ myv = bv; myj = bj; }
  }
  if (lane < 16){ topv[i*16+lane] = myv; topi[i*16+lane] = myj; }
}

// ---------------- dynamic layer pieces ----------------
// medge[e][c<Dx] = x_i[c]; [c>=Dx] = x_j[c-Dx] - x_i[c-Dx]
__global__ void k_build_medge(const float* __restrict__ x, int Dx,
                              const int* __restrict__ topi, int c0,
                              float* __restrict__ medge){
  int e = blockIdx.x;         // 0 .. NCH*17-1
  int c = threadIdx.x;        // 2*Dx threads
  int i = c0 + e / KEDGE;
  int slot = e % KEDGE;
  int j = (slot < KNN_K) ? topi[i*KNN_K + slot] : i;
  float v;
  if (c < Dx) v = x[(size_t)i*Dx + c];
  else        v = x[(size_t)j*Dx + (c-Dx)] - x[(size_t)i*Dx + (c-Dx)];
  medge[(size_t)e*(2*Dx) + c] = v;
}
__global__ void k_segmax_add(const float* __restrict__ mo, int H2, int c0,
                             float* __restrict__ out){
  int ii = blockIdx.x;        // local node
  int c = threadIdx.x;        // H2 threads
  float m = -INFINITY;
  for (int s=0;s<KEDGE;s++) m = fmaxf(m, mo[(size_t)(ii*KEDGE+s)*H2 + c]);
  out[(size_t)(c0+ii)*H2 + c] += m;
}

// ---------------- fusion pieces ----------------
__global__ void k_concat(const float* __restrict__ a, const float* __restrict__ b,
                         const float* __restrict__ c3, const float* __restrict__ d4,
                         const float* __restrict__ e5, float* __restrict__ o){
  int i = blockIdx.x;
  for (int c = threadIdx.x; c < 704; c += 256){
    float v;
    if (c < 64)       v = a[(size_t)i*64  + c];
    else if (c < 192) v = b[(size_t)i*128 + c - 64];
    else if (c < 384) v = c3[(size_t)i*192 + c - 192];
    else if (c < 512) v = d4[(size_t)i*128 + c - 384];
    else              v = e5[(size_t)i*192 + c - 512];
    o[(size_t)i*704 + c] = v;
  }
}
__global__ void k_bn_part(const float* __restrict__ X, int C,
                          float* __restrict__ psum, float* __restrict__ psq){
  int c = blockIdx.x*64 + (threadIdx.x & 63);
  int rl = threadIdx.x >> 6;
  int r0 = blockIdx.y * 512;
  float s = 0.f, q = 0.f;
  for (int r = r0 + rl; r < r0 + 512; r += 4){
    float v = X[(size_t)r*C + c];
    s += v; q += v*v;
  }
  __shared__ float ls[256], lq[256];
  ls[threadIdx.x] = s; lq[threadIdx.x] = q;
  __syncthreads();
  if (rl == 0){
    int t = threadIdx.x;
    psum[blockIdx.y*C + c] = ls[t] + ls[t+64] + ls[t+128] + ls[t+192];
    psq [blockIdx.y*C + c] = lq[t] + lq[t+64] + lq[t+128] + lq[t+192];
  }
}
__global__ void k_bn_stats(const float* __restrict__ psum, const float* __restrict__ psq,
                           int C, float* __restrict__ stat){
  int c = blockIdx.x*256 + threadIdx.x; if (c >= C) return;
  float s = 0.f, q = 0.f;
  for (int ch=0; ch<32; ch++){ s += psum[ch*C + c]; q += psq[ch*C + c]; }
  float m = s * (1.f/16384.f);
  float var = q * (1.f/16384.f) - m*m;
  stat[c] = m;
  stat[C + c] = rsqrtf(var + 1e-5f);
}
__global__ void k_bn_apply(float* __restrict__ X, int Cmask, int C,
                           const float* __restrict__ stat,
                           const float* __restrict__ g, const float* __restrict__ b,
                           int total){
  for (int idx = blockIdx.x*256 + threadIdx.x; idx < total; idx += gridDim.x*256){
    int c = idx & Cmask;
    float v = (X[idx] - stat[c]) * stat[C + c] * g[c] + b[c];
    X[idx] = (v >= 0.f) ? v : 0.2f*v;
  }
}

// ---------------- host ----------------
extern "C" void kernel_launch(void* const* d_in, const int* in_sizes, int n_in,
                              void* d_out, int out_size, void* d_ws, size_t ws_size,
                              hipStream_t stream) {
  (void)in_sizes; (void)n_in; (void)out_size; (void)ws_size;
  const float* x0      = (const float*)d_in[0];
  const float* ea      = (const float*)d_in[1];
  const int*   ei      = (const int*)d_in[2];
  const float* sg1_w1  = (const float*)d_in[4];
  const float* sg1_w2  = (const float*)d_in[5];
  const float* sg1_w3  = (const float*)d_in[6];
  const float* sg1_lin = (const float*)d_in[7];
  const float* sg2_w1  = (const float*)d_in[8];
  const float* sg2_w2  = (const float*)d_in[9];
  const float* sg2_w3  = (const float*)d_in[10];
  const float* sg2_lin = (const float*)d_in[11];
  const float* sg3_w1  = (const float*)d_in[12];
  const float* sg3_w2  = (const float*)d_in[13];
  const float* sg3_w3  = (const float*)d_in[14];
  const float* sg3_lin = (const float*)d_in[15];
  const float* dg1_m1  = (const float*)d_in[16];
  const float* dg1_m2  = (const float*)d_in[17];
  const float* dg1_lin = (const float*)d_in[18];
  const float* dg2_m1  = (const float*)d_in[19];
  const float* dg2_m2  = (const float*)d_in[20];
  const float* dg2_lin = (const float*)d_in[21];
  const float* f1_w    = (const float*)d_in[22];
  const float* f1_g    = (const float*)d_in[23];
  const float* f1_b    = (const float*)d_in[24];
  const float* f2_w1   = (const float*)d_in[25];
  const float* f2_g1   = (const float*)d_in[26];
  const float* f2_b1   = (const float*)d_in[27];
  const float* f2_w2   = (const float*)d_in[28];
  const float* f2_g2   = (const float*)d_in[29];
  const float* f2_b2   = (const float*)d_in[30];
  const float* f2_w3   = (const float*)d_in[31];
  float* out = (float*)d_out;

  // -------- workspace layout --------
  char* w = (char*)d_ws;
  size_t off = 0;
  auto alloc = [&](size_t bytes)->char*{
    char* p = w + off; off = (off + bytes + 255) & ~(size_t)255; return p;
  };
  float* sg1 = (float*)alloc((size_t)NN*64*4);
  float* sg2 = (float*)alloc((size_t)NN*128*4);
  float* sg3 = (float*)alloc((size_t)NN*192*4);
  float* dg1 = (float*)alloc((size_t)NN*128*4);
  float* dg2 = (float*)alloc((size_t)NN*192*4);
  float* f1  = (float*)alloc((size_t)NN*1024*4);
  float* bnp = (float*)alloc((size_t)2*32*1024*4);
  float* bns = (float*)alloc((size_t)2*1024*4);
  const size_t ARENA = 97000000;   // max(static 28.3MB, dyn 88.7MB, fusion 96.5MB)
  char* arena = alloc(ARENA);
  // static-phase views
  float* t1 = (float*)arena;                          // [NN,192]
  float* t2 = (float*)(arena + (size_t)NN*192*4);     // [NN,192]
  int* csr_off = (int*)(arena + (size_t)2*NN*192*4);
  int* csr_cnt = csr_off + (NN+1);
  int* csr_src = csr_cnt + NN;
  int* csr_eid = csr_src + NE;
  // dynamic-phase views (alias)
  float* xn    = (float*)arena;                                   // [NN,128]
  float* topv  = (float*)(arena + (size_t)NN*128*4);              // [NN,16]
  int*   topi  = (int*)((char*)topv + (size_t)NN*16*4);           // [NN,16]
  float* S     = (float*)((char*)topi + (size_t)NN*16*4);         // [NN,SCC]
  float* medge = S + (size_t)NN*SCC;                              // [NCH*17,256]
  float* mmid  = medge + (size_t)NCH*KEDGE*256;                   // [NCH*17,192]
  float* mout  = mmid  + (size_t)NCH*KEDGE*192;                   // [NCH*17,192]
  // fusion-phase views (alias)
  float* cat1 = (float*)arena;                   // [NN,704]
  float* h2   = cat1 + (size_t)NN*704;           // [NN,512]
  float* h3   = h2   + (size_t)NN*512;           // [NN,256]

  auto gemm = [&](const float* A, int lda, const float* B, int ldb,
                  float* C, int ldc, int M, int K, int Nc, float slope, int accum){
    dim3 g((Nc+63)/64, M/64);
    k_gemm<0><<<g, 256, 0, stream>>>(A, lda, B, ldb, C, ldc, K, Nc, slope, accum, 0, 0);
  };

  // -------- CSR build --------
  const int* srcp = ei;
  const int* dstp = ei + NE;
  k_fill_i32<<<(NN+255)/256, 256, 0, stream>>>(csr_cnt, 0, NN);
  k_hist<<<NE/256, 256, 0, stream>>>(dstp, csr_cnt);
  k_scan<<<1, 1024, 0, stream>>>(csr_cnt, csr_off);
  k_fill_i32<<<(NN+255)/256, 256, 0, stream>>>(csr_cnt, 0, NN);
  k_csr_fill<<<NE/256, 256, 0, stream>>>(srcp, dstp, csr_off, csr_cnt, csr_src, csr_eid);

  // -------- static layers --------
  auto static_layer = [&](const float* x, int Dx, const float* w1, const float* w2,
                          const float* w3, const float* lin,
                          int H1, int H2, float* outp){
    int DM = Dx + 64;
    k_static_segmax<<<NN, DM, 0, stream>>>(x, Dx, ea, csr_off, csr_src, csr_eid, t1);
    gemm(t1, DM, w1, H1, t2, H1, NN, DM, H1, 0.1f, 0);
    gemm(t2, H1, w2, H2, t1, H2, NN, H1, H2, 0.1f, 0);
    gemm(x, Dx, lin, H2, outp, H2, NN, Dx, H2, 0.1f, 0);   // lrelu(x@lin)
    gemm(t1, H2, w3, H2, outp, H2, NN, H2, H2, 0.1f, 1);   // += lrelu(h@w3)
  };
  static_layer(x0,  64, sg1_w1, sg1_w2, sg1_w3, sg1_lin,  96,  64, sg1);
  static_layer(sg1, 64, sg2_w1, sg2_w2, sg2_w3, sg2_lin, 128, 128, sg2);
  static_layer(sg2,128, sg3_w1, sg3_w2, sg3_w3, sg3_lin, 192, 192, sg3);

  // -------- dynamic layers --------
  auto dyn_layer = [&](const float* x, int Dx, const float* m1, const float* m2,
                       const float* lin, int H1, int H2, float* outp){
    k_normalize<<<NN, 64, 0, stream>>>(x, xn, Dx);
    k_fill_f32<<<(NN*16+255)/256, 256, 0, stream>>>(topv, -INFINITY, NN*16);
    k_fill_i32<<<(NN*16+255)/256, 256, 0, stream>>>(topi, 0x7fffffff, NN*16);
    for (int cb = 0; cb < NN; cb += SCC){
      dim3 g(SCC/64, NN/64);
      k_gemm<1><<<g, 256, 0, stream>>>(xn, Dx, xn + (size_t)cb*Dx, Dx,
                                       S, SCC, Dx, SCC, 1.0f, 0, 1, cb);
      k_topk_merge<<<NN, 64, 0, stream>>>(S, cb, topv, topi);
    }
    gemm(x, Dx, lin, H2, outp, H2, NN, Dx, H2, 0.1f, 0);   // lrelu(x@lin)
    for (int c0 = 0; c0 < NN; c0 += NCH){
      int R = NCH * KEDGE;
      k_build_medge<<<R, 2*Dx, 0, stream>>>(x, Dx, topi, c0, medge);
      gemm(medge, 2*Dx, m1, H1, mmid, H1, R, 2*Dx, H1, 0.2f, 0);
      gemm(mmid, H1, m2, H2, mout, H2, R, H1, H2, 0.2f, 0);
      k_segmax_add<<<NCH, H2, 0, stream>>>(mout, H2, c0, outp);
    }
  };
  dyn_layer(sg1,  64, dg1_m1, dg1_m2, dg1_lin, 128, 128, dg1);
  dyn_layer(dg1, 128, dg2_m1, dg2_m2, dg2_lin, 192, 192, dg2);

  // -------- fusion head --------
  auto bn = [&](float* X, int C, const float* g, const float* b){
    k_bn_part<<<dim3(C/64, 32), 256, 0, stream>>>(X, C, bnp, bnp + 32*1024);
    k_bn_stats<<<(C+255)/256, 256, 0, stream>>>(bnp, bnp + 32*1024, C, bns);
    k_bn_apply<<<2048, 256, 0, stream>>>(X, C-1, C, bns, g, b, NN*C);
  };
  k_concat<<<NN, 256, 0, stream>>>(sg1, dg1, dg2, sg2, sg3, cat1);
  gemm(cat1, 704, f1_w, 1024, f1, 1024, NN, 704, 1024, 1.0f, 0);
  bn(f1, 1024, f1_g, f1_b);
  gemm(f1,  1024, f2_w1,            512, h2, 512, NN, 1024, 512, 1.0f, 0);
  gemm(cat1, 704, f2_w1 + 1024*512, 512, h2, 512, NN,  704, 512, 1.0f, 1);
  bn(h2, 512, f2_g1, f2_b1);
  gemm(h2, 512, f2_w2, 256, h3, 256, NN, 512, 256, 1.0f, 0);
  bn(h3, 256, f2_g2, f2_b2);
  gemm(h3, 256, f2_w3, 128, out, 128, NN, 256, 128, 1.0f, 0);
}